// Round 11
// baseline (33.344 us; speedup 1.0000x reference)
//
#include <hip/hip_runtime.h>
#include <cmath>

#define WS 11

typedef __attribute__((ext_vector_type(8))) short short8;   // 8 bf16 (4 VGPRs)
typedef __attribute__((ext_vector_type(4))) float f32x4;
typedef __attribute__((ext_vector_type(4))) unsigned int u32x4;

struct GaussW { float g[WS]; };

__device__ __forceinline__ unsigned cvt_pk_bf16(float lo, float hi) {
    unsigned r;
    asm("v_cvt_pk_bf16_f32 %0, %1, %2" : "=v"(r) : "v"(lo), "v"(hi));
    return r;
}

// 24576 rows x 512 px. Wave = 16 rows x 32 px (TWO 16x16 output tiles).
// Conv as MFMA (R5-verified layouts): D[16 rows x 16 px] =
// A[16 x 32 window] * B[32 x 16 Toeplitz(g)]; 4 convs (u,v,u^2,v^2) share B.
// 24576 waves in 6144 blocks -> 4x residency churn (R5 had 1x, was
// latency-bound at 2.5% MfmaUtil). 8 up-front loads/lane, no branches,
// no LDS, per-wave partials.
__global__ __launch_bounds__(256) void ssim_mfma_kernel(
    const float* __restrict__ pred, const float* __restrict__ targ,
    GaussW gw, float* __restrict__ partials)
{
    const int t = threadIdx.x;
    const int lane = t & 63;
    const int wid = (blockIdx.x << 2) | (t >> 6);   // 0..24575
    const int rowgrp = wid >> 4;                    // 0..1535
    const int px0 = (wid & 15) << 5;                // 0,32,...,480
    const int l15 = lane & 15;
    const int kg = lane >> 4;

    const float C1 = 0.0001f, C2 = 0.0009f;

    // B fragment (Toeplitz): B[k][n] = g[k-n-3] (0 outside band),
    // n = l15, k = 8*kg + j.  [R5-verified]
    short8 bfrag;
    {
        u32x4 bu;
        #pragma unroll
        for (int jj = 0; jj < 4; ++jj) {
            const int k0 = 8 * kg + 2 * jj;
            float b0 = 0.f, b1 = 0.f;
            #pragma unroll
            for (int x = 0; x < WS; ++x) {
                b0 = (k0 - l15 - 3 == x) ? gw.g[x] : b0;
                b1 = (k0 - l15 - 2 == x) ? gw.g[x] : b1;
            }
            bu[jj] = cvt_pk_bf16(b0, b1);
        }
        bfrag = __builtin_bit_cast(short8, bu);
    }

    const int row = rowgrp * 16 + l15;
    const float* prow = pred + row * 512;
    const float* qrow = targ + row * 512;

    // Per-lane 8-px chunks for the two tiles. s in [-8, 512], multiple of 8:
    // chunks are fully in-bounds or fully out (zero-pad -> mask).
    const int s0 = px0 - 8 + 8 * kg;          // tile 0: [-8, 496]
    const int s1 = s0 + 16;                   // tile 1: [8, 512]
    const int sc0 = (s0 < 0) ? 0 : s0;
    const int sc1 = (s1 > 504) ? 504 : s1;
    const float m0 = (s0 < 0) ? 0.f : 1.f;
    const float m1 = (s1 > 504) ? 0.f : 1.f;

    // all 8 loads issued up front (16 rows x 32B strided gather, L1/L2-local)
    const f32x4 pa0 = *(const f32x4*)(prow + sc0);
    const f32x4 pa1 = *(const f32x4*)(prow + sc0 + 4);
    const f32x4 qa0 = *(const f32x4*)(qrow + sc0);
    const f32x4 qa1 = *(const f32x4*)(qrow + sc0 + 4);
    const f32x4 pb0 = *(const f32x4*)(prow + sc1);
    const f32x4 pb1 = *(const f32x4*)(prow + sc1 + 4);
    const f32x4 qb0 = *(const f32x4*)(qrow + sc1);
    const f32x4 qb1 = *(const f32x4*)(qrow + sc1 + 4);

    const f32x4 zero4 = {0.f, 0.f, 0.f, 0.f};
    float acc = 0.f;

    auto tile = [&](f32x4 p0, f32x4 p1, f32x4 q0, f32x4 q1,
                    float msk) -> float {
        f32x4 u0 = (p0 + q0) * msk, u1 = (p1 + q1) * msk;
        f32x4 v0 = (p0 - q0) * msk, v1 = (p1 - q1) * msk;
        f32x4 su0 = u0 * u0, su1 = u1 * u1;
        f32x4 sv0 = v0 * v0, sv1 = v1 * v1;

        u32x4 au, av, asu, asv;
        #pragma unroll
        for (int jj = 0; jj < 2; ++jj) {
            au[jj]    = cvt_pk_bf16(u0[2 * jj], u0[2 * jj + 1]);
            au[2+jj]  = cvt_pk_bf16(u1[2 * jj], u1[2 * jj + 1]);
            av[jj]    = cvt_pk_bf16(v0[2 * jj], v0[2 * jj + 1]);
            av[2+jj]  = cvt_pk_bf16(v1[2 * jj], v1[2 * jj + 1]);
            asu[jj]   = cvt_pk_bf16(su0[2 * jj], su0[2 * jj + 1]);
            asu[2+jj] = cvt_pk_bf16(su1[2 * jj], su1[2 * jj + 1]);
            asv[jj]   = cvt_pk_bf16(sv0[2 * jj], sv0[2 * jj + 1]);
            asv[2+jj] = cvt_pk_bf16(sv1[2 * jj], sv1[2 * jj + 1]);
        }

        const f32x4 DA = __builtin_amdgcn_mfma_f32_16x16x32_bf16(
            __builtin_bit_cast(short8, au), bfrag, zero4, 0, 0, 0);
        const f32x4 DB = __builtin_amdgcn_mfma_f32_16x16x32_bf16(
            __builtin_bit_cast(short8, av), bfrag, zero4, 0, 0, 0);
        const f32x4 DSU = __builtin_amdgcn_mfma_f32_16x16x32_bf16(
            __builtin_bit_cast(short8, asu), bfrag, zero4, 0, 0, 0);
        const f32x4 DSV = __builtin_amdgcn_mfma_f32_16x16x32_bf16(
            __builtin_bit_cast(short8, asv), bfrag, zero4, 0, 0, 0);

        // A=mu1+mu2, B=mu1-mu2, SU=m11+2m12+m22, SV=m11-2m12+m22  [R5 epi]
        float a = 0.f;
        #pragma unroll
        for (int j = 0; j < 4; ++j) {
            const float A = DA[j], B = DB[j], SU = DSU[j], SV = DSV[j];
            const float a2 = A * A, b2 = B * B;
            const float d2 = a2 - b2, t2 = a2 + b2;   // 4mu12, 2(mu1²+mu2²)
            const float ds = SU - SV, ts = SU + SV;   // 4m12,  2(m11+m22)
            const float num1 = fmaf(0.5f, d2, C1);
            const float den1 = fmaf(0.5f, t2, C1);
            const float num2 = fmaf(0.5f, ds - d2, C2);
            const float den2 = fmaf(0.5f, ts - t2, C2);
            a = fmaf(num1 * num2, __builtin_amdgcn_rcpf(den1 * den2), a);
        }
        return a;
    };

    acc = tile(pa0, pa1, qa0, qa1, m0) + tile(pb0, pb1, qb0, qb1, m1);

    // wave shuffle reduction; lane 0 writes this wave's partial. No barriers.
    #pragma unroll
    for (int off = 32; off > 0; off >>= 1)
        acc += __shfl_down(acc, off);
    if (lane == 0)
        partials[wid] = acc;
}

// Sum 24576 per-wave partials in double; the 10 zero-pad rows per (b,c)
// contribute ssim == 1 exactly: 16*3*10*512 = 245760 elements.
// Total elements: 16*3*522*512 = 12828672.
__global__ __launch_bounds__(1024) void ssim_final_kernel(
    const float* __restrict__ partials, float* __restrict__ out)
{
    const int t = threadIdx.x;
    double d = 0.0;
    #pragma unroll
    for (int i = 0; i < 24; ++i)
        d += (double)partials[t + 1024 * i];
    #pragma unroll
    for (int off = 32; off > 0; off >>= 1)
        d += __shfl_down(d, off);
    __shared__ double wsumd[16];
    const int lane = t & 63, wave = t >> 6;
    if (lane == 0) wsumd[wave] = d;
    __syncthreads();
    if (t == 0) {
        double s = 245760.0;
        #pragma unroll
        for (int i = 0; i < 16; ++i) s += wsumd[i];
        out[0] = (float)(1.0 - s / 12828672.0);
    }
}

extern "C" void kernel_launch(void* const* d_in, const int* in_sizes, int n_in,
                              void* d_out, int out_size, void* d_ws, size_t ws_size,
                              hipStream_t stream) {
    const float* pred = (const float*)d_in[0];
    const float* targ = (const float*)d_in[1];
    float* out = (float*)d_out;
    float* partials = (float*)d_ws;   // 24576 floats

    // Gaussian window, exactly as the reference (sigma=1.5, ws=11).
    GaussW gw;
    double graw[WS], s = 0.0;
    for (int i = 0; i < WS; ++i) {
        const double c = (double)(i - WS / 2);
        graw[i] = exp(-c * c / (2.0 * 1.5 * 1.5));
        s += graw[i];
    }
    for (int i = 0; i < WS; ++i) gw.g[i] = (float)(graw[i] / s);

    ssim_mfma_kernel<<<6144, 256, 0, stream>>>(pred, targ, gw, partials);
    ssim_final_kernel<<<1, 1024, 0, stream>>>(partials, out);
}

// Round 12
// 25.556 us; speedup vs baseline: 1.3047x; 1.3047x over previous
//
#include <hip/hip_runtime.h>
#include <hip/hip_fp16.h>
#include <cmath>

#define WS 11

struct GaussHalf {
    unsigned gA[WS];    // (g/sqrt2, g/sqrt2) as half2 bits — linear chain
    unsigned gS[WS];    // (g/2, g/2)         as half2 bits — square chain
    unsigned c11, c22;  // (C1,C1), (C2,C2)   as half2 bits
};

// 16*3*512 = 24576 rows of 512 floats. One wave per row, 8 px/lane,
// 3 rows/wave, prefetch next row during compute (R4 structure, best so far).
// 4-conv identity u=p+q, v=p-q; (u,v) packed as ONE __half2 so each conv
// tap is one full-rate v_pk_fma_f16 (packed f32 is half-rate on CDNA4 —
// f16 is the only packing that actually halves cycles).
// Epilogue identity in packed f16:
//   AB=(A,B)=(mu1+mu2,mu1-mu2)/sqrt2, SUV=(SU,SV)=conv(u^2,v^2)/2
//   t2d2 = (t2,-d2) = ab2 + swap(ab2)*(1,-1)     t2=mu1^2+mu2^2, d2=2mu1mu2
//   tsds = (ts,-ds) = SUV + swap(SUV)*(1,-1)     ts=m11+m22,     ds=2m12
//   dn1  = (den1,num1) = t2d2*(1,-1)+C1
//   dn2  = (den2,num2) = (tsds-t2d2)*(-1,... ) -> (ts-t2+C2, ds-d2+C2)
//   ssim = num1*num2 / (den1*den2)
__global__ __launch_bounds__(256) void ssim_row_kernel(
    const float* __restrict__ pred, const float* __restrict__ targ,
    GaussHalf gh, float* __restrict__ partials)
{
    const int t = threadIdx.x;
    const int lane = t & 63;
    const int wave = t >> 6;
    const int wave_id = blockIdx.x * 4 + wave;   // 0..8191

    const long long off = (long long)wave_id * 512 + 8 * lane;
    const float* prow = pred + off;
    const float* trow = targ + off;

    float4 P0 = *reinterpret_cast<const float4*>(prow);
    float4 P1 = *reinterpret_cast<const float4*>(prow + 4);
    float4 Q0 = *reinterpret_cast<const float4*>(trow);
    float4 Q1 = *reinterpret_cast<const float4*>(trow + 4);

    const __half2 pm = __halves2half2(__float2half(1.f), __float2half(-1.f));
    const __half2 C11 = __builtin_bit_cast(__half2, gh.c11);
    const __half2 C22 = __builtin_bit_cast(__half2, gh.c22);

    float acc = 0.f;
    #pragma unroll
    for (int r = 0; r < 3; ++r) {
        // prefetch next row (8192 rows apart) before computing this one
        float4 nP0, nP1, nQ0, nQ1;
        if (r < 2) {
            const float* pn = prow + (long long)(r + 1) * 8192 * 512;
            const float* tn = trow + (long long)(r + 1) * 8192 * 512;
            nP0 = *reinterpret_cast<const float4*>(pn);
            nP1 = *reinterpret_cast<const float4*>(pn + 4);
            nQ0 = *reinterpret_cast<const float4*>(tn);
            nQ1 = *reinterpret_cast<const float4*>(tn + 4);
        }

        // w[i] = (u,v) as half2 at row px (8*lane - 5 + i)
        __half2 w[18];
        {
            const float pv[8] = {P0.x, P0.y, P0.z, P0.w, P1.x, P1.y, P1.z, P1.w};
            const float qv[8] = {Q0.x, Q0.y, Q0.z, Q0.w, Q1.x, Q1.y, Q1.z, Q1.w};
            #pragma unroll
            for (int i = 0; i < 8; ++i)
                w[5 + i] = __floats2half2_rn(pv[i] + qv[i], pv[i] - qv[i]);
        }
        // halos from neighbor lanes (one u32 shuffle moves both u and v);
        // zero at row edges = the reference's W zero-padding
        #pragma unroll
        for (int i = 0; i < 5; ++i) {
            const unsigned lu =
                __shfl_up(__builtin_bit_cast(unsigned, w[8 + i]), 1);
            const unsigned ru =
                __shfl_down(__builtin_bit_cast(unsigned, w[5 + i]), 1);
            w[i]      = __builtin_bit_cast(__half2, (lane == 0)  ? 0u : lu);
            w[13 + i] = __builtin_bit_cast(__half2, (lane == 63) ? 0u : ru);
        }
        __half2 s[18];
        #pragma unroll
        for (int i = 0; i < 18; ++i) s[i] = __hmul2(w[i], w[i]);

        #pragma unroll
        for (int px = 0; px < 8; ++px) {
            __half2 AB  = __builtin_bit_cast(__half2, 0u);
            __half2 SUV = __builtin_bit_cast(__half2, 0u);
            #pragma unroll
            for (int k = 0; k < WS; ++k) {
                AB  = __hfma2(__builtin_bit_cast(__half2, gh.gA[k]),
                              w[px + k], AB);
                SUV = __hfma2(__builtin_bit_cast(__half2, gh.gS[k]),
                              s[px + k], SUV);
            }
            const __half2 ab2  = __hmul2(AB, AB);                   // (A2,B2)
            const __half2 t2d2 = __hfma2(__lowhigh2highlow(ab2), pm, ab2);
            const __half2 tsds = __hfma2(__lowhigh2highlow(SUV), pm, SUV);
            const __half2 dn1  = __hfma2(t2d2, pm, C11);   // (den1, num1)
            const __half2 dl   = __hsub2(tsds, t2d2);      // (ts-t2, d2-ds)
            const __half2 dn2  = __hfma2(dl, pm, C22);     // (den2, num2)
            const __half2 nd   = __hmul2(dn1, dn2);        // (dd, nn)
            const float dd = __half2float(__low2half(nd));
            const float nn = __half2float(__high2half(nd));
            acc = fmaf(nn, __builtin_amdgcn_rcpf(dd), acc);
        }

        if (r < 2) { P0 = nP0; P1 = nP1; Q0 = nQ0; Q1 = nQ1; }
    }

    // wave reduction, then block combine, partials (no atomics)
    #pragma unroll
    for (int offr = 32; offr > 0; offr >>= 1)
        acc += __shfl_down(acc, offr);
    __shared__ float wsum[4];
    if (lane == 0) wsum[wave] = acc;
    __syncthreads();
    if (t == 0)
        partials[blockIdx.x] = wsum[0] + wsum[1] + wsum[2] + wsum[3];
}

// Sum 2048 block partials in double; the 10 zero-pad rows per (b,c)
// contribute ssim == 1 exactly: 16*3*10*512 = 245760 elements.
// Total elements: 16*3*522*512 = 12828672.
__global__ __launch_bounds__(256) void ssim_final_kernel(
    const float* __restrict__ partials, float* __restrict__ out)
{
    const int t = threadIdx.x;
    double d = 0.0;
    #pragma unroll
    for (int i = 0; i < 8; ++i)
        d += (double)partials[t + 256 * i];
    #pragma unroll
    for (int offr = 32; offr > 0; offr >>= 1)
        d += __shfl_down(d, offr);
    __shared__ double wsumd[4];
    const int lane = t & 63, wave = t >> 6;
    if (lane == 0) wsumd[wave] = d;
    __syncthreads();
    if (t == 0) {
        const double s = wsumd[0] + wsumd[1] + wsumd[2] + wsumd[3] + 245760.0;
        out[0] = (float)(1.0 - s / 12828672.0);
    }
}

static unsigned packh2(float x) {
    const __half h = __float2half(x);
    unsigned short hb;
    __builtin_memcpy(&hb, &h, 2);
    return ((unsigned)hb << 16) | hb;
}

extern "C" void kernel_launch(void* const* d_in, const int* in_sizes, int n_in,
                              void* d_out, int out_size, void* d_ws, size_t ws_size,
                              hipStream_t stream) {
    const float* pred = (const float*)d_in[0];
    const float* targ = (const float*)d_in[1];
    float* out = (float*)d_out;
    float* partials = (float*)d_ws;   // 2048 floats

    // Gaussian window exactly as the reference (sigma=1.5, ws=11),
    // prescaled: gA = g/sqrt(2) (linear chain), gS = g/2 (square chain),
    // duplicated into (h,h) half2 constants.
    GaussHalf gh;
    double graw[WS], s = 0.0;
    for (int i = 0; i < WS; ++i) {
        const double c = (double)(i - WS / 2);
        graw[i] = exp(-c * c / (2.0 * 1.5 * 1.5));
        s += graw[i];
    }
    for (int i = 0; i < WS; ++i) {
        const double g = graw[i] / s;
        gh.gA[i] = packh2((float)(g * 0.70710678118654752));
        gh.gS[i] = packh2((float)(g * 0.5));
    }
    gh.c11 = packh2(0.0001f);
    gh.c22 = packh2(0.0009f);

    ssim_row_kernel<<<2048, 256, 0, stream>>>(pred, targ, gh, partials);
    ssim_final_kernel<<<1, 256, 0, stream>>>(partials, out);
}

// Round 13
// 24.890 us; speedup vs baseline: 1.3397x; 1.0268x over previous
//
#include <hip/hip_runtime.h>
#include <hip/hip_fp16.h>
#include <cmath>

#define WS 11

struct GaussHalf {
    unsigned gA[WS];    // (g/sqrt2, g/sqrt2) as half2 bits — linear chain
    unsigned gS[WS];    // (g/2, g/2)         as half2 bits — square chain
    unsigned c11, c22;  // (C1,C1), (C2,C2)   as half2 bits
};

// 16*3*512 = 24576 rows of 512 floats. ONE wave per row, 8 px/lane.
// R12's proven f16 math verbatim; restructured for occupancy: working set
// ~55 VGPR, __launch_bounds__(256,8) forces <=64 VGPR -> 8 waves/SIMD
// (m69 cliff), 6144 blocks -> 24 blocks/CU of churn. TLP hides the row
// load latency instead of the failed prefetch/pipeline attempts (R8-R10).
__global__ __launch_bounds__(256, 8) void ssim_row_kernel(
    const float* __restrict__ pred, const float* __restrict__ targ,
    GaussHalf gh, float* __restrict__ partials)
{
    const int t = threadIdx.x;
    const int lane = t & 63;
    const int wid = (blockIdx.x << 2) | (t >> 6);   // 0..24575

    const long long off = (long long)wid * 512 + 8 * lane;
    const float* prow = pred + off;
    const float* trow = targ + off;

    const float4 P0 = *reinterpret_cast<const float4*>(prow);
    const float4 P1 = *reinterpret_cast<const float4*>(prow + 4);
    const float4 Q0 = *reinterpret_cast<const float4*>(trow);
    const float4 Q1 = *reinterpret_cast<const float4*>(trow + 4);

    const __half2 pm = __halves2half2(__float2half(1.f), __float2half(-1.f));
    const __half2 C11 = __builtin_bit_cast(__half2, gh.c11);
    const __half2 C22 = __builtin_bit_cast(__half2, gh.c22);

    // w[i] = (u,v) as half2 at row px (8*lane - 5 + i)
    __half2 w[18];
    {
        const float pv[8] = {P0.x, P0.y, P0.z, P0.w, P1.x, P1.y, P1.z, P1.w};
        const float qv[8] = {Q0.x, Q0.y, Q0.z, Q0.w, Q1.x, Q1.y, Q1.z, Q1.w};
        #pragma unroll
        for (int i = 0; i < 8; ++i)
            w[5 + i] = __floats2half2_rn(pv[i] + qv[i], pv[i] - qv[i]);
    }
    // halos from neighbor lanes (one u32 shuffle moves both u and v);
    // zero at row edges = the reference's W zero-padding
    #pragma unroll
    for (int i = 0; i < 5; ++i) {
        const unsigned lu =
            __shfl_up(__builtin_bit_cast(unsigned, w[8 + i]), 1);
        const unsigned ru =
            __shfl_down(__builtin_bit_cast(unsigned, w[5 + i]), 1);
        w[i]      = __builtin_bit_cast(__half2, (lane == 0)  ? 0u : lu);
        w[13 + i] = __builtin_bit_cast(__half2, (lane == 63) ? 0u : ru);
    }
    __half2 s[18];
    #pragma unroll
    for (int i = 0; i < 18; ++i) s[i] = __hmul2(w[i], w[i]);

    float acc = 0.f;
    #pragma unroll
    for (int px = 0; px < 8; ++px) {
        __half2 AB  = __builtin_bit_cast(__half2, 0u);
        __half2 SUV = __builtin_bit_cast(__half2, 0u);
        #pragma unroll
        for (int k = 0; k < WS; ++k) {
            AB  = __hfma2(__builtin_bit_cast(__half2, gh.gA[k]),
                          w[px + k], AB);
            SUV = __hfma2(__builtin_bit_cast(__half2, gh.gS[k]),
                          s[px + k], SUV);
        }
        const __half2 ab2  = __hmul2(AB, AB);                   // (A2,B2)
        const __half2 t2d2 = __hfma2(__lowhigh2highlow(ab2), pm, ab2);
        const __half2 tsds = __hfma2(__lowhigh2highlow(SUV), pm, SUV);
        const __half2 dn1  = __hfma2(t2d2, pm, C11);   // (den1, num1)
        const __half2 dl   = __hsub2(tsds, t2d2);      // (ts-t2, d2-ds)
        const __half2 dn2  = __hfma2(dl, pm, C22);     // (den2, num2)
        const __half2 nd   = __hmul2(dn1, dn2);        // (dd, nn)
        const float dd = __half2float(__low2half(nd));
        const float nn = __half2float(__high2half(nd));
        acc = fmaf(nn, __builtin_amdgcn_rcpf(dd), acc);
    }

    // wave shuffle reduction; lane 0 writes this wave's partial.
    // No LDS, no barriers.
    #pragma unroll
    for (int offr = 32; offr > 0; offr >>= 1)
        acc += __shfl_down(acc, offr);
    if (lane == 0)
        partials[wid] = acc;
}

// Sum 24576 per-wave partials in double; the 10 zero-pad rows per (b,c)
// contribute ssim == 1 exactly: 16*3*10*512 = 245760 elements.
// Total elements: 16*3*522*512 = 12828672.
__global__ __launch_bounds__(1024) void ssim_final_kernel(
    const float* __restrict__ partials, float* __restrict__ out)
{
    const int t = threadIdx.x;
    double d = 0.0;
    #pragma unroll
    for (int i = 0; i < 24; ++i)
        d += (double)partials[t + 1024 * i];
    #pragma unroll
    for (int offr = 32; offr > 0; offr >>= 1)
        d += __shfl_down(d, offr);
    __shared__ double wsumd[16];
    const int lane = t & 63, wave = t >> 6;
    if (lane == 0) wsumd[wave] = d;
    __syncthreads();
    if (t == 0) {
        double s = 245760.0;
        #pragma unroll
        for (int i = 0; i < 16; ++i) s += wsumd[i];
        out[0] = (float)(1.0 - s / 12828672.0);
    }
}

static unsigned packh2(float x) {
    const __half h = __float2half(x);
    unsigned short hb;
    __builtin_memcpy(&hb, &h, 2);
    return ((unsigned)hb << 16) | hb;
}

extern "C" void kernel_launch(void* const* d_in, const int* in_sizes, int n_in,
                              void* d_out, int out_size, void* d_ws, size_t ws_size,
                              hipStream_t stream) {
    const float* pred = (const float*)d_in[0];
    const float* targ = (const float*)d_in[1];
    float* out = (float*)d_out;
    float* partials = (float*)d_ws;   // 24576 floats

    // Gaussian window exactly as the reference (sigma=1.5, ws=11),
    // prescaled: gA = g/sqrt(2) (linear chain), gS = g/2 (square chain),
    // duplicated into (h,h) half2 constants.
    GaussHalf gh;
    double graw[WS], s = 0.0;
    for (int i = 0; i < WS; ++i) {
        const double c = (double)(i - WS / 2);
        graw[i] = exp(-c * c / (2.0 * 1.5 * 1.5));
        s += graw[i];
    }
    for (int i = 0; i < WS; ++i) {
        const double g = graw[i] / s;
        gh.gA[i] = packh2((float)(g * 0.70710678118654752));
        gh.gS[i] = packh2((float)(g * 0.5));
    }
    gh.c11 = packh2(0.0001f);
    gh.c22 = packh2(0.0009f);

    ssim_row_kernel<<<6144, 256, 0, stream>>>(pred, targ, gh, partials);
    ssim_final_kernel<<<1, 1024, 0, stream>>>(partials, out);
}